// Round 2
// baseline (1983.341 us; speedup 1.0000x reference)
//
#include <hip/hip_runtime.h>

#define SDIM 2048
#define DDIM 128
#define NBH  64
#define BR   128   // q rows per block (4 waves x 32)
#define BC   64    // keys per tile
#define PSTRIDE 72 // bf16 elems; conflict-free b128 A-frag reads of P

using bf16x8 = __attribute__((ext_vector_type(8))) short;
using f32x4  = __attribute__((ext_vector_type(4))) float;

static __device__ __forceinline__ short f2bf(float x) {
    unsigned u = __float_as_uint(x);
    u += 0x7fff + ((u >> 16) & 1);   // RNE
    return (short)(u >> 16);
}
static __device__ __forceinline__ unsigned pack2(float a, float b) {
    return ((unsigned)(unsigned short)f2bf(a)) |
           (((unsigned)(unsigned short)f2bf(b)) << 16);
}

// ---- prep 1: K fp32 -> bf16 (elementwise) ----
__global__ __launch_bounds__(256) void kconv_kernel(const float* __restrict__ K,
                                                    unsigned short* __restrict__ Kc)
{
    size_t i = ((size_t)blockIdx.x * 256 + threadIdx.x) * 4;
    float4 v = *(const float4*)(K + i);
    uint2 o;
    o.x = pack2(v.x, v.y);
    o.y = pack2(v.z, v.w);
    *(uint2*)(Kc + i) = o;
}

// ---- prep 2: V fp32 [bh][s][d] -> bf16 V^T [bh][d][s] ----
__global__ __launch_bounds__(256) void vtrans_kernel(const float* __restrict__ V,
                                                     unsigned short* __restrict__ Vt)
{
    __shared__ float t[32][33];
    const int bh = blockIdx.z;
    const int s0 = blockIdx.x * 32;
    const int d0 = blockIdx.y * 32;
    const int x = threadIdx.x & 31;
    const int y = threadIdx.x >> 5;
    const float* Vb = V + (size_t)bh * SDIM * DDIM;
    unsigned short* Vtb = Vt + (size_t)bh * SDIM * DDIM;
#pragma unroll
    for (int i = 0; i < 4; ++i) {
        int r = y + i * 8;
        t[r][x] = Vb[(size_t)(s0 + r) * DDIM + d0 + x];
    }
    __syncthreads();
#pragma unroll
    for (int i = 0; i < 4; ++i) {
        int r = y + i * 8;
        Vtb[(size_t)(d0 + r) * SDIM + s0 + x] = (unsigned short)f2bf(t[x][r]);
    }
}

// ---- mask tile load: 32 scalar dwords per lane-row group ----
static __device__ __forceinline__ void load_mask(const float* __restrict__ Mb,
                                                 int q0, int wave, int quad, int n16,
                                                 int kcol, float (&mk)[2][4][4])
{
#pragma unroll
    for (int rt = 0; rt < 2; ++rt) {
        const int rowb = q0 + wave * 32 + rt * 16 + quad * 4;
        const float* mpb = Mb + (size_t)rowb * SDIM + kcol + n16;
#pragma unroll
        for (int ct = 0; ct < 4; ++ct)
#pragma unroll
            for (int r = 0; r < 4; ++r)
                mk[rt][ct][r] = mpb[(size_t)r * SDIM + ct * 16];
    }
}

// ---- one k-tile body; mkc = current tile's mask (already loaded),
//      mkn = next tile's mask (prefetched here) ----
static __device__ __forceinline__ void ktile_body(
    int k0, int q0, int wave, int quad, int n16, int lane,
    const float* __restrict__ Mb,
    const unsigned short* __restrict__ Kb, const unsigned short* __restrict__ Vb,
    unsigned short* __restrict__ PsW,
    const bf16x8 (&qf)[2][4],
    f32x4 (&acc)[2][8], float (&mrow)[2][4], float (&lrow)[2][4],
    float (&mkc)[2][4][4], float (&mkn)[2][4][4])
{
    const f32x4 zero4 = {0.f, 0.f, 0.f, 0.f};

    // ---- S = Q K^T : B-frags from global (L2-warm); issued FIRST so the
    //      MFMA vmcnt wait does not force the mask prefetch to drain ----
    f32x4 s[2][4];
#pragma unroll
    for (int rt = 0; rt < 2; ++rt)
#pragma unroll
        for (int ct = 0; ct < 4; ++ct) s[rt][ct] = zero4;
#pragma unroll
    for (int dt = 0; dt < 4; ++dt) {
#pragma unroll
        for (int ct = 0; ct < 4; ++ct) {
            bf16x8 kf = *(const bf16x8*)(Kb + (size_t)(k0 + ct * 16 + n16) * DDIM + dt * 32 + quad * 8);
            s[0][ct] = __builtin_amdgcn_mfma_f32_16x16x32_bf16(qf[0][dt], kf, s[0][ct], 0, 0, 0);
            s[1][ct] = __builtin_amdgcn_mfma_f32_16x16x32_bf16(qf[1][dt], kf, s[1][ct], 0, 0, 0);
        }
    }

    // ---- prefetch NEXT tile's mask: issued after all K loads, consumed next
    //      iteration; its ~900cy HBM latency hides under softmax+P-pack.
    //      Fences pin issue position (scheduler must not hoist into K queue). ----
    __builtin_amdgcn_sched_barrier(0);
    load_mask(Mb, q0, wave, quad, n16, (k0 + BC) & (SDIM - 1), mkn);
    __builtin_amdgcn_sched_barrier(0);

    // ---- mask add (current tile's mask: retired for free by the K wait) ----
#pragma unroll
    for (int rt = 0; rt < 2; ++rt)
#pragma unroll
        for (int ct = 0; ct < 4; ++ct)
#pragma unroll
            for (int r = 0; r < 4; ++r)
                s[rt][ct][r] += mkc[rt][ct][r];

    // ---- online softmax: batched shuffle chains (8 independent rows) ----
    float mx[2][4];
#pragma unroll
    for (int rt = 0; rt < 2; ++rt)
#pragma unroll
        for (int r = 0; r < 4; ++r)
            mx[rt][r] = fmaxf(fmaxf(s[rt][0][r], s[rt][1][r]),
                              fmaxf(s[rt][2][r], s[rt][3][r]));
#pragma unroll
    for (int st = 1; st <= 8; st <<= 1)
#pragma unroll
        for (int rt = 0; rt < 2; ++rt)
#pragma unroll
            for (int r = 0; r < 4; ++r)
                mx[rt][r] = fmaxf(mx[rt][r], __shfl_xor(mx[rt][r], st));

    // exact defer-rescale: when no row sees a new max, al==1.0 exactly ->
    // skipping the rescale is bitwise identical. Wave-uniform branch.
    int anynew = 0;
#pragma unroll
    for (int rt = 0; rt < 2; ++rt)
#pragma unroll
        for (int r = 0; r < 4; ++r)
            anynew |= (mx[rt][r] > mrow[rt][r]) ? 1 : 0;
    if (__ballot(anynew) != 0ull) {
#pragma unroll
        for (int rt = 0; rt < 2; ++rt)
#pragma unroll
            for (int r = 0; r < 4; ++r) {
                float mnew = fmaxf(mrow[rt][r], mx[rt][r]);
                float al = exp2f((mrow[rt][r] - mnew) * 1.44269504f);
                mrow[rt][r] = mnew;
                lrow[rt][r] *= al;
#pragma unroll
                for (int nt = 0; nt < 8; ++nt) acc[rt][nt][r] *= al;
            }
    }

    float rs[2][4];
#pragma unroll
    for (int rt = 0; rt < 2; ++rt)
#pragma unroll
        for (int r = 0; r < 4; ++r) {
            float t = 0.f;
#pragma unroll
            for (int ct = 0; ct < 4; ++ct) {
                float pv = exp2f((s[rt][ct][r] - mrow[rt][r]) * 1.44269504f);
                s[rt][ct][r] = pv;
                t += pv;
            }
            rs[rt][r] = t;
        }
#pragma unroll
    for (int st = 1; st <= 8; st <<= 1)
#pragma unroll
        for (int rt = 0; rt < 2; ++rt)
#pragma unroll
            for (int r = 0; r < 4; ++r)
                rs[rt][r] += __shfl_xor(rs[rt][r], st);
#pragma unroll
    for (int rt = 0; rt < 2; ++rt)
#pragma unroll
        for (int r = 0; r < 4; ++r)
            lrow[rt][r] += rs[rt][r];

    // ---- P: C-layout regs -> LDS (own wave region; no barrier needed) ----
#pragma unroll
    for (int rt = 0; rt < 2; ++rt)
#pragma unroll
        for (int ct = 0; ct < 4; ++ct)
#pragma unroll
            for (int r = 0; r < 4; ++r)
                PsW[(rt * 16 + (lane >> 4) * 4 + r) * PSTRIDE + ct * 16 + n16] =
                    (unsigned short)f2bf(s[rt][ct][r]);

    // ---- P A-frags (lgkmcnt ordering within wave suffices) ----
    bf16x8 pa[2][2];
#pragma unroll
    for (int rt = 0; rt < 2; ++rt)
#pragma unroll
        for (int kt = 0; kt < 2; ++kt)
            pa[rt][kt] = *(const bf16x8*)(&PsW[(rt * 16 + n16) * PSTRIDE + kt * 32 + quad * 8]);

    // ---- O += P V : V frags from global; V-wait drains the mask prefetch
    //      only here, AFTER softmax has covered its latency ----
#pragma unroll
    for (int nt = 0; nt < 8; ++nt) {
#pragma unroll
        for (int kt = 0; kt < 2; ++kt) {
            bf16x8 vf = *(const bf16x8*)(Vb + (size_t)(nt * 16 + n16) * SDIM + k0 + kt * 32 + quad * 8);
            acc[0][nt] = __builtin_amdgcn_mfma_f32_16x16x32_bf16(pa[0][kt], vf, acc[0][nt], 0, 0, 0);
            acc[1][nt] = __builtin_amdgcn_mfma_f32_16x16x32_bf16(pa[1][kt], vf, acc[1][nt], 0, 0, 0);
        }
    }
}

// ---- main: flash attention, K/V frags from global bf16, no barriers,
//      mask software-pipelined one k-tile ahead ----
__global__ __launch_bounds__(256, 2) void fattn_kernel(
    const float* __restrict__ Q, const float* __restrict__ M,
    const unsigned short* __restrict__ Kc, const unsigned short* __restrict__ Vt,
    float* __restrict__ O)
{
    // XCD-grouped decode: all 16 q-tiles of one bh share flat%8 -> one XCD's L2
    // holds that head's K+V (1 MB) for all its blocks. Bijective over 1024.
    const int flat = blockIdx.x;
    const int slot = flat >> 3;
    const int bh   = (flat & 7) * 8 + (slot >> 4);
    const int qt   = slot & 15;

    const int tid  = threadIdx.x;
    const int wave = tid >> 6;
    const int lane = tid & 63;
    const int quad = lane >> 4;
    const int n16  = lane & 15;
    const int q0   = qt * BR;

    const float* Qb = Q + (size_t)bh * SDIM * DDIM;
    const float* Mb = M + (size_t)bh * SDIM * SDIM;
    const unsigned short* Kb = Kc + (size_t)bh * SDIM * DDIM;  // [s][d] bf16
    const unsigned short* Vb = Vt + (size_t)bh * SDIM * DDIM;  // [d][s] bf16
    float* Ob = O + (size_t)bh * SDIM * DDIM;

    __shared__ __align__(16) unsigned short Ps[4][32 * PSTRIDE];
    unsigned short* PsW = Ps[wave];

    // Q A-fragments, pre-scaled, in regs for the whole kernel
    const float scale = 0.08838834764831845f;
    bf16x8 qf[2][4];
#pragma unroll
    for (int rt = 0; rt < 2; ++rt) {
        int row = q0 + wave * 32 + rt * 16 + n16;
        const float* qp = Qb + (size_t)row * DDIM + quad * 8;
#pragma unroll
        for (int dt = 0; dt < 4; ++dt) {
            const float* p = qp + dt * 32;
            float4 a = *(const float4*)p;
            float4 b = *(const float4*)(p + 4);
            bf16x8 f;
            f[0] = f2bf(a.x * scale); f[1] = f2bf(a.y * scale);
            f[2] = f2bf(a.z * scale); f[3] = f2bf(a.w * scale);
            f[4] = f2bf(b.x * scale); f[5] = f2bf(b.y * scale);
            f[6] = f2bf(b.z * scale); f[7] = f2bf(b.w * scale);
            qf[rt][dt] = f;
        }
    }

    f32x4 acc[2][8];
    const f32x4 zero4 = {0.f, 0.f, 0.f, 0.f};
#pragma unroll
    for (int rt = 0; rt < 2; ++rt)
#pragma unroll
        for (int nt = 0; nt < 8; ++nt) acc[rt][nt] = zero4;
    float mrow[2][4], lrow[2][4];
#pragma unroll
    for (int rt = 0; rt < 2; ++rt)
#pragma unroll
        for (int r = 0; r < 4; ++r) { mrow[rt][r] = -1e30f; lrow[rt][r] = 0.f; }

    // explicit double-buffer in named registers (no runtime indexing -> no scratch)
    float mkA[2][4][4], mkB[2][4][4];
    load_mask(Mb, q0, wave, quad, n16, 0, mkA);

#pragma unroll 1
    for (int k0 = 0; k0 < SDIM; k0 += 2 * BC) {
        ktile_body(k0,      q0, wave, quad, n16, lane, Mb, Kb, Vb, PsW,
                   qf, acc, mrow, lrow, mkA, mkB);
        ktile_body(k0 + BC, q0, wave, quad, n16, lane, Mb, Kb, Vb, PsW,
                   qf, acc, mrow, lrow, mkB, mkA);
    }

    // ---- epilogue ----
#pragma unroll
    for (int rt = 0; rt < 2; ++rt) {
#pragma unroll
        for (int r = 0; r < 4; ++r) {
            float inv = 1.0f / lrow[rt][r];
            int row = q0 + wave * 32 + rt * 16 + quad * 4 + r;
            float* op = Ob + (size_t)row * DDIM + n16;
#pragma unroll
            for (int nt = 0; nt < 8; ++nt)
                op[nt * 16] = acc[rt][nt][r] * inv;
        }
    }
}

extern "C" void kernel_launch(void* const* d_in, const int* in_sizes, int n_in,
                              void* d_out, int out_size, void* d_ws, size_t ws_size,
                              hipStream_t stream) {
    const float* Q = (const float*)d_in[0];
    const float* K = (const float*)d_in[1];
    const float* V = (const float*)d_in[2];
    const float* M = (const float*)d_in[3];
    float* O = (float*)d_out;

    unsigned short* Kc = (unsigned short*)d_ws;
    unsigned short* Vt = Kc + (size_t)NBH * SDIM * DDIM;

    // prep: K -> bf16, V -> bf16 transposed
    size_t nElem = (size_t)NBH * SDIM * DDIM;            // 16.7M
    kconv_kernel<<<dim3(nElem / (256 * 4)), 256, 0, stream>>>(K, Kc);
    vtrans_kernel<<<dim3(SDIM / 32, DDIM / 32, NBH), 256, 0, stream>>>(V, Vt);

    fattn_kernel<<<dim3((SDIM / BR) * NBH), 256, 0, stream>>>(Q, M, Kc, Vt, O);
}

// Round 4
// 1937.915 us; speedup vs baseline: 1.0234x; 1.0234x over previous
//
#include <hip/hip_runtime.h>

#define SDIM 2048
#define DDIM 128
#define NBH  64
#define BR   128   // q rows per block (4 waves x 32)
#define BC   64    // keys per tile
#define PSTRIDE 72 // bf16 elems; conflict-free b128 A-frag reads of P

using bf16x8 = __attribute__((ext_vector_type(8))) short;
using f32x4  = __attribute__((ext_vector_type(4))) float;

static __device__ __forceinline__ short f2bf(float x) {
    unsigned u = __float_as_uint(x);
    u += 0x7fff + ((u >> 16) & 1);   // RNE
    return (short)(u >> 16);
}
static __device__ __forceinline__ unsigned pack2(float a, float b) {
    return ((unsigned)(unsigned short)f2bf(a)) |
           (((unsigned)(unsigned short)f2bf(b)) << 16);
}

// ---- prep 1: K fp32 -> bf16 (elementwise); thread 0 also zeroes the mask flag ----
__global__ __launch_bounds__(256) void kconv_kernel(const float* __restrict__ K,
                                                    unsigned short* __restrict__ Kc,
                                                    unsigned* __restrict__ flag)
{
    if (flag != nullptr && blockIdx.x == 0 && threadIdx.x == 0) *flag = 0u;
    size_t i = ((size_t)blockIdx.x * 256 + threadIdx.x) * 4;
    float4 v = *(const float4*)(K + i);
    uint2 o;
    o.x = pack2(v.x, v.y);
    o.y = pack2(v.z, v.w);
    *(uint2*)(Kc + i) = o;
}

// ---- prep 2: V fp32 [bh][s][d] -> bf16 V^T [bh][d][s] ----
__global__ __launch_bounds__(256) void vtrans_kernel(const float* __restrict__ V,
                                                     unsigned short* __restrict__ Vt)
{
    __shared__ float t[32][33];
    const int bh = blockIdx.z;
    const int s0 = blockIdx.x * 32;
    const int d0 = blockIdx.y * 32;
    const int x = threadIdx.x & 31;
    const int y = threadIdx.x >> 5;
    const float* Vb = V + (size_t)bh * SDIM * DDIM;
    unsigned short* Vtb = Vt + (size_t)bh * SDIM * DDIM;
#pragma unroll
    for (int i = 0; i < 4; ++i) {
        int r = y + i * 8;
        t[r][x] = Vb[(size_t)(s0 + r) * DDIM + d0 + x];
    }
    __syncthreads();
#pragma unroll
    for (int i = 0; i < 4; ++i) {
        int r = y + i * 8;
        Vtb[(size_t)(d0 + r) * SDIM + s0 + x] = (unsigned short)f2bf(t[x][r]);
    }
}

// ---- prep 3: OR all mask bits -> flag. Bitwise-nonzero is conservative:
//      -0.0 / NaN / Inf all route to the exact slow path. Streaming read. ----
__global__ __launch_bounds__(256) void maskscan_kernel(const uint4* __restrict__ M4,
                                                       unsigned* __restrict__ flag)
{
    const size_t n4 = (size_t)NBH * SDIM * SDIM / 4;   // 67,108,864
    unsigned acc = 0;
    for (size_t i = (size_t)blockIdx.x * 256 + threadIdx.x; i < n4;
         i += (size_t)gridDim.x * 256) {
        uint4 v = M4[i];
        acc |= v.x | v.y | v.z | v.w;
    }
    if (acc) *flag = 1u;   // racy-but-idempotent; zeros case never stores
}

// ---- mask tile load (slow path only) ----
static __device__ __forceinline__ void load_mask(const float* __restrict__ Mb,
                                                 int q0, int wave, int quad, int n16,
                                                 int kcol, float (&mk)[2][4][4])
{
#pragma unroll
    for (int rt = 0; rt < 2; ++rt) {
        const int rowb = q0 + wave * 32 + rt * 16 + quad * 4;
        const float* mpb = Mb + (size_t)rowb * SDIM + kcol + n16;
#pragma unroll
        for (int ct = 0; ct < 4; ++ct)
#pragma unroll
            for (int r = 0; r < 4; ++r)
                mk[rt][ct][r] = mpb[(size_t)r * SDIM + ct * 16];
    }
}

// ---- one k-tile. K frags batched into explicit regs (one counted wait,
//      16 loads in flight) instead of serialized load->use chains. ----
template<bool MASKED>
static __device__ __forceinline__ void ktile_body(
    int k0, int q0, int wave, int quad, int n16, int lane,
    const float* __restrict__ Mb,
    const unsigned short* __restrict__ Kb, const unsigned short* __restrict__ Vb,
    unsigned short* __restrict__ PsW,
    const bf16x8 (&qf)[2][4],
    f32x4 (&acc)[2][8], float (&mrow)[2][4], float (&lrow)[2][4])
{
    const f32x4 zero4 = {0.f, 0.f, 0.f, 0.f};

    // ---- batched K-frag loads: all 16 issued before any MFMA ----
    bf16x8 kfr[4][4];
#pragma unroll
    for (int dt = 0; dt < 4; ++dt)
#pragma unroll
        for (int ct = 0; ct < 4; ++ct)
            kfr[dt][ct] = *(const bf16x8*)(Kb + (size_t)(k0 + ct * 16 + n16) * DDIM + dt * 32 + quad * 8);

    // ---- mask loads (issued after K; K waits don't drain them) ----
    float mk[2][4][4];
    if constexpr (MASKED)
        load_mask(Mb, q0, wave, quad, n16, k0, mk);

    // ---- S = Q K^T ----
    f32x4 s[2][4];
#pragma unroll
    for (int rt = 0; rt < 2; ++rt)
#pragma unroll
        for (int ct = 0; ct < 4; ++ct) s[rt][ct] = zero4;
#pragma unroll
    for (int dt = 0; dt < 4; ++dt) {
#pragma unroll
        for (int ct = 0; ct < 4; ++ct) {
            s[0][ct] = __builtin_amdgcn_mfma_f32_16x16x32_bf16(qf[0][dt], kfr[dt][ct], s[0][ct], 0, 0, 0);
            s[1][ct] = __builtin_amdgcn_mfma_f32_16x16x32_bf16(qf[1][dt], kfr[dt][ct], s[1][ct], 0, 0, 0);
        }
    }

    // ---- mask add (fast path: adding +0.0f is a no-op through exp) ----
    if constexpr (MASKED) {
#pragma unroll
        for (int rt = 0; rt < 2; ++rt)
#pragma unroll
            for (int ct = 0; ct < 4; ++ct)
#pragma unroll
                for (int r = 0; r < 4; ++r)
                    s[rt][ct][r] += mk[rt][ct][r];
    }

    // ---- online softmax: batched shuffle chains (8 independent rows) ----
    float mx[2][4];
#pragma unroll
    for (int rt = 0; rt < 2; ++rt)
#pragma unroll
        for (int r = 0; r < 4; ++r)
            mx[rt][r] = fmaxf(fmaxf(s[rt][0][r], s[rt][1][r]),
                              fmaxf(s[rt][2][r], s[rt][3][r]));
#pragma unroll
    for (int st = 1; st <= 8; st <<= 1)
#pragma unroll
        for (int rt = 0; rt < 2; ++rt)
#pragma unroll
            for (int r = 0; r < 4; ++r)
                mx[rt][r] = fmaxf(mx[rt][r], __shfl_xor(mx[rt][r], st));

    // exact defer-rescale: if no row sees a new max, al==1.0 -> skip is bitwise id.
    int anynew = 0;
#pragma unroll
    for (int rt = 0; rt < 2; ++rt)
#pragma unroll
        for (int r = 0; r < 4; ++r)
            anynew |= (mx[rt][r] > mrow[rt][r]) ? 1 : 0;
    if (__ballot(anynew) != 0ull) {
#pragma unroll
        for (int rt = 0; rt < 2; ++rt)
#pragma unroll
            for (int r = 0; r < 4; ++r) {
                float mnew = fmaxf(mrow[rt][r], mx[rt][r]);
                float al = exp2f((mrow[rt][r] - mnew) * 1.44269504f);
                mrow[rt][r] = mnew;
                lrow[rt][r] *= al;
#pragma unroll
                for (int nt = 0; nt < 8; ++nt) acc[rt][nt][r] *= al;
            }
    }

    float rs[2][4];
#pragma unroll
    for (int rt = 0; rt < 2; ++rt)
#pragma unroll
        for (int r = 0; r < 4; ++r) {
            float t = 0.f;
#pragma unroll
            for (int ct = 0; ct < 4; ++ct) {
                float pv = exp2f((s[rt][ct][r] - mrow[rt][r]) * 1.44269504f);
                s[rt][ct][r] = pv;
                t += pv;
            }
            rs[rt][r] = t;
        }
#pragma unroll
    for (int st = 1; st <= 8; st <<= 1)
#pragma unroll
        for (int rt = 0; rt < 2; ++rt)
#pragma unroll
            for (int r = 0; r < 4; ++r)
                rs[rt][r] += __shfl_xor(rs[rt][r], st);
#pragma unroll
    for (int rt = 0; rt < 2; ++rt)
#pragma unroll
        for (int r = 0; r < 4; ++r)
            lrow[rt][r] += rs[rt][r];

    // ---- P: C-layout regs -> LDS (own wave region; no barrier needed) ----
#pragma unroll
    for (int rt = 0; rt < 2; ++rt)
#pragma unroll
        for (int ct = 0; ct < 4; ++ct)
#pragma unroll
            for (int r = 0; r < 4; ++r)
                PsW[(rt * 16 + (lane >> 4) * 4 + r) * PSTRIDE + ct * 16 + n16] =
                    (unsigned short)f2bf(s[rt][ct][r]);

    // ---- P A-frags (lgkmcnt ordering within wave suffices) ----
    bf16x8 pa[2][2];
#pragma unroll
    for (int rt = 0; rt < 2; ++rt)
#pragma unroll
        for (int kt = 0; kt < 2; ++kt)
            pa[rt][kt] = *(const bf16x8*)(&PsW[(rt * 16 + n16) * PSTRIDE + kt * 32 + quad * 8]);

    // ---- O += P V : V frags inline; kfr dead by now -> regalloc can hoist ----
#pragma unroll
    for (int nt = 0; nt < 8; ++nt) {
#pragma unroll
        for (int kt = 0; kt < 2; ++kt) {
            bf16x8 vf = *(const bf16x8*)(Vb + (size_t)(nt * 16 + n16) * SDIM + k0 + kt * 32 + quad * 8);
            acc[0][nt] = __builtin_amdgcn_mfma_f32_16x16x32_bf16(pa[0][kt], vf, acc[0][nt], 0, 0, 0);
            acc[1][nt] = __builtin_amdgcn_mfma_f32_16x16x32_bf16(pa[1][kt], vf, acc[1][nt], 0, 0, 0);
        }
    }
}

// ---- main: flash attention; zero-mask fast path skips all mask traffic ----
__global__ __launch_bounds__(256, 2) void fattn_kernel(
    const float* __restrict__ Q, const float* __restrict__ M,
    const unsigned short* __restrict__ Kc, const unsigned short* __restrict__ Vt,
    const unsigned* __restrict__ flag,
    float* __restrict__ O)
{
    // XCD-grouped decode: all 16 q-tiles of one bh share flat%8 -> one XCD's L2
    // holds that head's K+V (1 MB) for all its blocks. Bijective over 1024.
    const int flat = blockIdx.x;
    const int slot = flat >> 3;
    const int bh   = (flat & 7) * 8 + (slot >> 4);
    const int qt   = slot & 15;

    const int tid  = threadIdx.x;
    const int wave = tid >> 6;
    const int lane = tid & 63;
    const int quad = lane >> 4;
    const int n16  = lane & 15;
    const int q0   = qt * BR;

    const float* Qb = Q + (size_t)bh * SDIM * DDIM;
    const float* Mb = M + (size_t)bh * SDIM * SDIM;
    const unsigned short* Kb = Kc + (size_t)bh * SDIM * DDIM;  // [s][d] bf16
    const unsigned short* Vb = Vt + (size_t)bh * SDIM * DDIM;  // [d][s] bf16
    float* Ob = O + (size_t)bh * SDIM * DDIM;

    // nullptr flag (no workspace room) -> always take the exact masked path
    const bool masked = (flag == nullptr) || (*flag != 0u);   // wave-uniform

    __shared__ __align__(16) unsigned short Ps[4][32 * PSTRIDE];
    unsigned short* PsW = Ps[wave];

    // Q A-fragments, pre-scaled, in regs for the whole kernel
    const float scale = 0.08838834764831845f;
    bf16x8 qf[2][4];
#pragma unroll
    for (int rt = 0; rt < 2; ++rt) {
        int row = q0 + wave * 32 + rt * 16 + n16;
        const float* qp = Qb + (size_t)row * DDIM + quad * 8;
#pragma unroll
        for (int dt = 0; dt < 4; ++dt) {
            const float* p = qp + dt * 32;
            float4 a = *(const float4*)p;
            float4 b = *(const float4*)(p + 4);
            bf16x8 f;
            f[0] = f2bf(a.x * scale); f[1] = f2bf(a.y * scale);
            f[2] = f2bf(a.z * scale); f[3] = f2bf(a.w * scale);
            f[4] = f2bf(b.x * scale); f[5] = f2bf(b.y * scale);
            f[6] = f2bf(b.z * scale); f[7] = f2bf(b.w * scale);
            qf[rt][dt] = f;
        }
    }

    f32x4 acc[2][8];
    const f32x4 zero4 = {0.f, 0.f, 0.f, 0.f};
#pragma unroll
    for (int rt = 0; rt < 2; ++rt)
#pragma unroll
        for (int nt = 0; nt < 8; ++nt) acc[rt][nt] = zero4;
    float mrow[2][4], lrow[2][4];
#pragma unroll
    for (int rt = 0; rt < 2; ++rt)
#pragma unroll
        for (int r = 0; r < 4; ++r) { mrow[rt][r] = -1e30f; lrow[rt][r] = 0.f; }

    if (!masked) {
#pragma unroll 1
        for (int k0 = 0; k0 < SDIM; k0 += BC)
            ktile_body<false>(k0, q0, wave, quad, n16, lane, Mb, Kb, Vb, PsW,
                              qf, acc, mrow, lrow);
    } else {
#pragma unroll 1
        for (int k0 = 0; k0 < SDIM; k0 += BC)
            ktile_body<true>(k0, q0, wave, quad, n16, lane, Mb, Kb, Vb, PsW,
                             qf, acc, mrow, lrow);
    }

    // ---- epilogue ----
#pragma unroll
    for (int rt = 0; rt < 2; ++rt) {
#pragma unroll
        for (int r = 0; r < 4; ++r) {
            float inv = 1.0f / lrow[rt][r];
            int row = q0 + wave * 32 + rt * 16 + quad * 4 + r;
            float* op = Ob + (size_t)row * DDIM + n16;
#pragma unroll
            for (int nt = 0; nt < 8; ++nt)
                op[nt * 16] = acc[rt][nt][r] * inv;
        }
    }
}

extern "C" void kernel_launch(void* const* d_in, const int* in_sizes, int n_in,
                              void* d_out, int out_size, void* d_ws, size_t ws_size,
                              hipStream_t stream) {
    const float* Q = (const float*)d_in[0];
    const float* K = (const float*)d_in[1];
    const float* V = (const float*)d_in[2];
    const float* M = (const float*)d_in[3];
    float* O = (float*)d_out;

    const size_t nElem = (size_t)NBH * SDIM * DDIM;      // 16.7M elems per array
    unsigned short* Kc = (unsigned short*)d_ws;
    unsigned short* Vt = Kc + nElem;

    // flag lives past Kc+Vt ONLY if the workspace has room; else flag=nullptr
    // and fattn takes the always-masked exact path (no OOB write possible).
    const size_t kvBytes = 2 * nElem * sizeof(unsigned short);   // 67,108,864
    unsigned* flag = (ws_size >= kvBytes + sizeof(unsigned))
                   ? (unsigned*)((char*)d_ws + kvBytes) : nullptr;

    // prep: K -> bf16 (+flag=0), V -> bf16 transposed, mask zero-scan
    kconv_kernel<<<dim3(nElem / (256 * 4)), 256, 0, stream>>>(K, Kc, flag);
    vtrans_kernel<<<dim3(SDIM / 32, DDIM / 32, NBH), 256, 0, stream>>>(V, Vt);
    if (flag != nullptr)
        maskscan_kernel<<<dim3(2048), 256, 0, stream>>>((const uint4*)M, flag);

    fattn_kernel<<<dim3((SDIM / BR) * NBH), 256, 0, stream>>>(Q, M, Kc, Vt, flag, O);
}

// Round 5
// 1767.174 us; speedup vs baseline: 1.1223x; 1.0966x over previous
//
#include <hip/hip_runtime.h>

#define SDIM 2048
#define DDIM 128
#define NBH  64
#define BR   128   // q rows per block (4 waves x 32)
#define BC   64    // keys per tile
#define PSTRIDE 72 // bf16 elems; conflict-free b128 A-frag reads of P

using bf16x8 = __attribute__((ext_vector_type(8))) short;
using f32x4  = __attribute__((ext_vector_type(4))) float;

typedef const __attribute__((address_space(1))) void* gvp;
typedef __attribute__((address_space(3))) void* lvp;

static __device__ __forceinline__ short f2bf(float x) {
    unsigned u = __float_as_uint(x);
    u += 0x7fff + ((u >> 16) & 1);   // RNE
    return (short)(u >> 16);
}
static __device__ __forceinline__ unsigned pack2(float a, float b) {
    return ((unsigned)(unsigned short)f2bf(a)) |
           (((unsigned)(unsigned short)f2bf(b)) << 16);
}

// ---- prep 1: K fp32 -> bf16 (elementwise); thread 0 also zeroes the mask flag ----
__global__ __launch_bounds__(256) void kconv_kernel(const float* __restrict__ K,
                                                    unsigned short* __restrict__ Kc,
                                                    unsigned* __restrict__ flag)
{
    if (flag != nullptr && blockIdx.x == 0 && threadIdx.x == 0) *flag = 0u;
    size_t i = ((size_t)blockIdx.x * 256 + threadIdx.x) * 4;
    float4 v = *(const float4*)(K + i);
    uint2 o;
    o.x = pack2(v.x, v.y);
    o.y = pack2(v.z, v.w);
    *(uint2*)(Kc + i) = o;
}

// ---- prep 2: V fp32 [bh][s][d] -> bf16 V^T [bh][d][s] ----
__global__ __launch_bounds__(256) void vtrans_kernel(const float* __restrict__ V,
                                                     unsigned short* __restrict__ Vt)
{
    __shared__ float t[32][33];
    const int bh = blockIdx.z;
    const int s0 = blockIdx.x * 32;
    const int d0 = blockIdx.y * 32;
    const int x = threadIdx.x & 31;
    const int y = threadIdx.x >> 5;
    const float* Vb = V + (size_t)bh * SDIM * DDIM;
    unsigned short* Vtb = Vt + (size_t)bh * SDIM * DDIM;
#pragma unroll
    for (int i = 0; i < 4; ++i) {
        int r = y + i * 8;
        t[r][x] = Vb[(size_t)(s0 + r) * DDIM + d0 + x];
    }
    __syncthreads();
#pragma unroll
    for (int i = 0; i < 4; ++i) {
        int r = y + i * 8;
        Vtb[(size_t)(d0 + r) * SDIM + s0 + x] = (unsigned short)f2bf(t[x][r]);
    }
}

// ---- prep 3: OR all mask bits -> flag (conservative; streaming) ----
__global__ __launch_bounds__(256) void maskscan_kernel(const uint4* __restrict__ M4,
                                                       unsigned* __restrict__ flag)
{
    const size_t n4 = (size_t)NBH * SDIM * SDIM / 4;
    unsigned acc = 0;
    for (size_t i = (size_t)blockIdx.x * 256 + threadIdx.x; i < n4;
         i += (size_t)gridDim.x * 256) {
        uint4 v = M4[i];
        acc |= v.x | v.y | v.z | v.w;
    }
    if (acc) *flag = 1u;   // racy-but-idempotent; zeros case never stores
}

// ---- mask tile load (slow path only) ----
static __device__ __forceinline__ void load_mask(const float* __restrict__ Mb,
                                                 int q0, int wave, int quad, int n16,
                                                 int kcol, float (&mk)[2][4][4])
{
#pragma unroll
    for (int rt = 0; rt < 2; ++rt) {
        const int rowb = q0 + wave * 32 + rt * 16 + quad * 4;
        const float* mpb = Mb + (size_t)rowb * SDIM + kcol + n16;
#pragma unroll
        for (int ct = 0; ct < 4; ++ct)
#pragma unroll
            for (int r = 0; r < 4; ++r)
                mk[rt][ct][r] = mpb[(size_t)r * SDIM + ct * 16];
    }
}

// ---- one k-tile with cooperative LDS-staged K/V (XOR-swizzled, rule #21:
//      linear LDS dest + inverse-swizzled global SOURCE + swizzled ds_read) ----
template<bool MASKED>
static __device__ __forceinline__ void ktile_body(
    int k0, int q0, int wave, int quad, int n16, int lane,
    const float* __restrict__ Mb,
    const unsigned short* __restrict__ Kb, const unsigned short* __restrict__ Vb,
    char* __restrict__ Kl, char* __restrict__ Vl,
    unsigned short* __restrict__ PsW,
    const bf16x8 (&qf)[2][4],
    f32x4 (&acc)[2][8], float (&mrow)[2][4], float (&lrow)[2][4])
{
    const f32x4 zero4 = {0.f, 0.f, 0.f, 0.f};

    // ---- phase 1: stage K tile [64 rows x 256B] and V^T tile [128 rows x 128B].
    //      HW writes LDS linearly (base + lane*16); source col pre-swizzled so a
    //      swizzled ds_read returns the true element. swz = (row&7)<<4. ----
#pragma unroll
    for (int j = 0; j < 4; ++j) {               // K: wave covers rows [wave*16, +16)
        const int row = wave * 16 + j * 4 + quad;
        const int src = (n16 * 16) ^ ((row & 7) << 4);
        const char* gp = (const char*)(Kb + (size_t)(k0 + row) * DDIM) + src;
        char* lp = Kl + wave * 4096 + j * 1024;  // wave-uniform dest base
        __builtin_amdgcn_global_load_lds((gvp)gp, (lvp)lp, 16, 0, 0);
    }
#pragma unroll
    for (int j = 0; j < 4; ++j) {               // V: wave covers rows [wave*32, +32)
        const int row = wave * 32 + j * 8 + (lane >> 3);
        const int src = ((lane & 7) * 16) ^ ((row & 7) << 4);
        const char* gp = (const char*)(Vb + (size_t)row * SDIM + k0) + src;
        char* lp = Vl + wave * 4096 + j * 1024;
        __builtin_amdgcn_global_load_lds((gvp)gp, (lvp)lp, 16, 0, 0);
    }

    // ---- mask loads (issued behind the stage; drained by the same barrier) ----
    float mk[2][4][4];
    if constexpr (MASKED)
        load_mask(Mb, q0, wave, quad, n16, k0, mk);

    __syncthreads();   // drains vmcnt (global_load_lds + mask) and lgkm

    const int swzr = (n16 & 7) << 4;   // read-side swizzle: row&7 == n16&7 here

    // ---- S = Q K^T : A=Q regs, B=K frags from swizzled LDS ----
    f32x4 s[2][4];
#pragma unroll
    for (int rt = 0; rt < 2; ++rt)
#pragma unroll
        for (int ct = 0; ct < 4; ++ct) s[rt][ct] = zero4;
#pragma unroll
    for (int dt = 0; dt < 4; ++dt) {
        bf16x8 kf[4];
#pragma unroll
        for (int ct = 0; ct < 4; ++ct)
            kf[ct] = *(const bf16x8*)(Kl + (ct * 16 + n16) * 256 +
                                      ((dt * 64 + quad * 16) ^ swzr));
        __builtin_amdgcn_s_setprio(1);
#pragma unroll
        for (int ct = 0; ct < 4; ++ct) {
            s[0][ct] = __builtin_amdgcn_mfma_f32_16x16x32_bf16(qf[0][dt], kf[ct], s[0][ct], 0, 0, 0);
            s[1][ct] = __builtin_amdgcn_mfma_f32_16x16x32_bf16(qf[1][dt], kf[ct], s[1][ct], 0, 0, 0);
        }
        __builtin_amdgcn_s_setprio(0);
    }

    // ---- mask add (fast path: +0.0f is identity through exp) ----
    if constexpr (MASKED) {
#pragma unroll
        for (int rt = 0; rt < 2; ++rt)
#pragma unroll
            for (int ct = 0; ct < 4; ++ct)
#pragma unroll
                for (int r = 0; r < 4; ++r)
                    s[rt][ct][r] += mk[rt][ct][r];
    }

    // ---- online softmax: batched shuffle chains (8 independent rows) ----
    float mx[2][4];
#pragma unroll
    for (int rt = 0; rt < 2; ++rt)
#pragma unroll
        for (int r = 0; r < 4; ++r)
            mx[rt][r] = fmaxf(fmaxf(s[rt][0][r], s[rt][1][r]),
                              fmaxf(s[rt][2][r], s[rt][3][r]));
#pragma unroll
    for (int st = 1; st <= 8; st <<= 1)
#pragma unroll
        for (int rt = 0; rt < 2; ++rt)
#pragma unroll
            for (int r = 0; r < 4; ++r)
                mx[rt][r] = fmaxf(mx[rt][r], __shfl_xor(mx[rt][r], st));

    // exact defer-rescale: if no row sees a new max, al==1.0 -> skip is bitwise id.
    int anynew = 0;
#pragma unroll
    for (int rt = 0; rt < 2; ++rt)
#pragma unroll
        for (int r = 0; r < 4; ++r)
            anynew |= (mx[rt][r] > mrow[rt][r]) ? 1 : 0;
    if (__ballot(anynew) != 0ull) {
#pragma unroll
        for (int rt = 0; rt < 2; ++rt)
#pragma unroll
            for (int r = 0; r < 4; ++r) {
                float mnew = fmaxf(mrow[rt][r], mx[rt][r]);
                float al = exp2f((mrow[rt][r] - mnew) * 1.44269504f);
                mrow[rt][r] = mnew;
                lrow[rt][r] *= al;
#pragma unroll
                for (int nt = 0; nt < 8; ++nt) acc[rt][nt][r] *= al;
            }
    }

    float rs[2][4];
#pragma unroll
    for (int rt = 0; rt < 2; ++rt)
#pragma unroll
        for (int r = 0; r < 4; ++r) {
            float t = 0.f;
#pragma unroll
            for (int ct = 0; ct < 4; ++ct) {
                float pv = exp2f((s[rt][ct][r] - mrow[rt][r]) * 1.44269504f);
                s[rt][ct][r] = pv;
                t += pv;
            }
            rs[rt][r] = t;
        }
#pragma unroll
    for (int st = 1; st <= 8; st <<= 1)
#pragma unroll
        for (int rt = 0; rt < 2; ++rt)
#pragma unroll
            for (int r = 0; r < 4; ++r)
                rs[rt][r] += __shfl_xor(rs[rt][r], st);
#pragma unroll
    for (int rt = 0; rt < 2; ++rt)
#pragma unroll
        for (int r = 0; r < 4; ++r)
            lrow[rt][r] += rs[rt][r];

    // ---- P: C-layout regs -> LDS (own wave region; no barrier needed) ----
#pragma unroll
    for (int rt = 0; rt < 2; ++rt)
#pragma unroll
        for (int ct = 0; ct < 4; ++ct)
#pragma unroll
            for (int r = 0; r < 4; ++r)
                PsW[(rt * 16 + (lane >> 4) * 4 + r) * PSTRIDE + ct * 16 + n16] =
                    (unsigned short)f2bf(s[rt][ct][r]);

    // ---- P A-frags (lgkmcnt ordering within wave suffices) ----
    bf16x8 pa[2][2];
#pragma unroll
    for (int rt = 0; rt < 2; ++rt)
#pragma unroll
        for (int kt = 0; kt < 2; ++kt)
            pa[rt][kt] = *(const bf16x8*)(&PsW[(rt * 16 + n16) * PSTRIDE + kt * 32 + quad * 8]);

    // ---- O += P V : B=V frags from swizzled LDS ----
#pragma unroll
    for (int nt = 0; nt < 8; ++nt) {
        bf16x8 vf[2];
#pragma unroll
        for (int kt = 0; kt < 2; ++kt)
            vf[kt] = *(const bf16x8*)(Vl + (nt * 16 + n16) * 128 +
                                      ((kt * 64 + quad * 16) ^ swzr));
        __builtin_amdgcn_s_setprio(1);
#pragma unroll
        for (int kt = 0; kt < 2; ++kt) {
            acc[0][nt] = __builtin_amdgcn_mfma_f32_16x16x32_bf16(pa[0][kt], vf[kt], acc[0][nt], 0, 0, 0);
            acc[1][nt] = __builtin_amdgcn_mfma_f32_16x16x32_bf16(pa[1][kt], vf[kt], acc[1][nt], 0, 0, 0);
        }
        __builtin_amdgcn_s_setprio(0);
    }
}

// ---- main: flash attention; zero-mask fast path skips all mask traffic ----
__global__ __launch_bounds__(256, 2) void fattn_kernel(
    const float* __restrict__ Q, const float* __restrict__ M,
    const unsigned short* __restrict__ Kc, const unsigned short* __restrict__ Vt,
    const unsigned* __restrict__ flag,
    float* __restrict__ O)
{
    // XCD-grouped decode: all 16 q-tiles of one bh share flat%8 -> one XCD's L2
    const int flat = blockIdx.x;
    const int slot = flat >> 3;
    const int bh   = (flat & 7) * 8 + (slot >> 4);
    const int qt   = slot & 15;

    const int tid  = threadIdx.x;
    const int wave = tid >> 6;
    const int lane = tid & 63;
    const int quad = lane >> 4;
    const int n16  = lane & 15;
    const int q0   = qt * BR;

    const float* Qb = Q + (size_t)bh * SDIM * DDIM;
    const float* Mb = M + (size_t)bh * SDIM * SDIM;
    const unsigned short* Kb = Kc + (size_t)bh * SDIM * DDIM;  // [s][d] bf16
    const unsigned short* Vb = Vt + (size_t)bh * SDIM * DDIM;  // [d][s] bf16
    float* Ob = O + (size_t)bh * SDIM * DDIM;

    const bool masked = (flag == nullptr) || (*flag != 0u);   // wave-uniform

    __shared__ __align__(16) char Kl[64 * 256];                       // 16 KB
    __shared__ __align__(16) char Vl[128 * 128];                      // 16 KB
    __shared__ __align__(16) unsigned short Ps[4][32 * PSTRIDE];      // 18 KB
    unsigned short* PsW = Ps[wave];

    // Q A-fragments, pre-scaled, in regs for the whole kernel
    const float scale = 0.08838834764831845f;
    bf16x8 qf[2][4];
#pragma unroll
    for (int rt = 0; rt < 2; ++rt) {
        int row = q0 + wave * 32 + rt * 16 + n16;
        const float* qp = Qb + (size_t)row * DDIM + quad * 8;
#pragma unroll
        for (int dt = 0; dt < 4; ++dt) {
            const float* p = qp + dt * 32;
            float4 a = *(const float4*)p;
            float4 b = *(const float4*)(p + 4);
            bf16x8 f;
            f[0] = f2bf(a.x * scale); f[1] = f2bf(a.y * scale);
            f[2] = f2bf(a.z * scale); f[3] = f2bf(a.w * scale);
            f[4] = f2bf(b.x * scale); f[5] = f2bf(b.y * scale);
            f[6] = f2bf(b.z * scale); f[7] = f2bf(b.w * scale);
            qf[rt][dt] = f;
        }
    }

    f32x4 acc[2][8];
    const f32x4 zero4 = {0.f, 0.f, 0.f, 0.f};
#pragma unroll
    for (int rt = 0; rt < 2; ++rt)
#pragma unroll
        for (int nt = 0; nt < 8; ++nt) acc[rt][nt] = zero4;
    float mrow[2][4], lrow[2][4];
#pragma unroll
    for (int rt = 0; rt < 2; ++rt)
#pragma unroll
        for (int r = 0; r < 4; ++r) { mrow[rt][r] = -1e30f; lrow[rt][r] = 0.f; }

    if (!masked) {
#pragma unroll 1
        for (int k0 = 0; k0 < SDIM; k0 += BC) {
            __syncthreads();   // Kl/Vl free (prev tile's ds_reads done)
            ktile_body<false>(k0, q0, wave, quad, n16, lane, Mb, Kb, Vb,
                              Kl, Vl, PsW, qf, acc, mrow, lrow);
        }
    } else {
#pragma unroll 1
        for (int k0 = 0; k0 < SDIM; k0 += BC) {
            __syncthreads();
            ktile_body<true>(k0, q0, wave, quad, n16, lane, Mb, Kb, Vb,
                             Kl, Vl, PsW, qf, acc, mrow, lrow);
        }
    }

    // ---- epilogue ----
#pragma unroll
    for (int rt = 0; rt < 2; ++rt) {
#pragma unroll
        for (int r = 0; r < 4; ++r) {
            float inv = 1.0f / lrow[rt][r];
            int row = q0 + wave * 32 + rt * 16 + quad * 4 + r;
            float* op = Ob + (size_t)row * DDIM + n16;
#pragma unroll
            for (int nt = 0; nt < 8; ++nt)
                op[nt * 16] = acc[rt][nt][r] * inv;
        }
    }
}

extern "C" void kernel_launch(void* const* d_in, const int* in_sizes, int n_in,
                              void* d_out, int out_size, void* d_ws, size_t ws_size,
                              hipStream_t stream) {
    const float* Q = (const float*)d_in[0];
    const float* K = (const float*)d_in[1];
    const float* V = (const float*)d_in[2];
    const float* M = (const float*)d_in[3];
    float* O = (float*)d_out;

    const size_t nElem = (size_t)NBH * SDIM * DDIM;      // 16.7M elems per array
    unsigned short* Kc = (unsigned short*)d_ws;
    unsigned short* Vt = Kc + nElem;

    // flag lives past Kc+Vt ONLY if the workspace has room; else flag=nullptr
    // and fattn takes the always-masked exact path (no OOB write possible).
    const size_t kvBytes = 2 * nElem * sizeof(unsigned short);   // 67,108,864
    unsigned* flag = (ws_size >= kvBytes + sizeof(unsigned))
                   ? (unsigned*)((char*)d_ws + kvBytes) : nullptr;

    kconv_kernel<<<dim3(nElem / (256 * 4)), 256, 0, stream>>>(K, Kc, flag);
    vtrans_kernel<<<dim3(SDIM / 32, DDIM / 32, NBH), 256, 0, stream>>>(V, Vt);
    if (flag != nullptr)
        maskscan_kernel<<<dim3(2048), 256, 0, stream>>>((const uint4*)M, flag);

    fattn_kernel<<<dim3((SDIM / BR) * NBH), 256, 0, stream>>>(Q, M, Kc, Vt, flag, O);
}

// Round 6
// 1735.467 us; speedup vs baseline: 1.1428x; 1.0183x over previous
//
#include <hip/hip_runtime.h>

#define SDIM 2048
#define DDIM 128
#define NBH  64
#define BR   128   // q rows per block (4 waves x 32)
#define BC   64    // keys per tile
#define PSTRIDE 72 // bf16 elems; conflict-free b128 A-frag reads of P

using bf16x8 = __attribute__((ext_vector_type(8))) short;
using f32x4  = __attribute__((ext_vector_type(4))) float;

typedef const __attribute__((address_space(1))) void* gvp;
typedef __attribute__((address_space(3))) void* lvp;

static __device__ __forceinline__ short f2bf(float x) {
    unsigned u = __float_as_uint(x);
    u += 0x7fff + ((u >> 16) & 1);   // RNE
    return (short)(u >> 16);
}
static __device__ __forceinline__ unsigned pack2(float a, float b) {
    return ((unsigned)(unsigned short)f2bf(a)) |
           (((unsigned)(unsigned short)f2bf(b)) << 16);
}

// ---- prep 1: K fp32 -> bf16 (elementwise) ----
__global__ __launch_bounds__(256) void kconv_kernel(const float* __restrict__ K,
                                                    unsigned short* __restrict__ Kc)
{
    size_t i = ((size_t)blockIdx.x * 256 + threadIdx.x) * 4;
    float4 v = *(const float4*)(K + i);
    uint2 o;
    o.x = pack2(v.x, v.y);
    o.y = pack2(v.z, v.w);
    *(uint2*)(Kc + i) = o;
}

// ---- prep 2: V fp32 [bh][s][d] -> bf16 V^T [bh][d][s] ----
__global__ __launch_bounds__(256) void vtrans_kernel(const float* __restrict__ V,
                                                     unsigned short* __restrict__ Vt)
{
    __shared__ float t[32][33];
    const int bh = blockIdx.z;
    const int s0 = blockIdx.x * 32;
    const int d0 = blockIdx.y * 32;
    const int x = threadIdx.x & 31;
    const int y = threadIdx.x >> 5;
    const float* Vb = V + (size_t)bh * SDIM * DDIM;
    unsigned short* Vtb = Vt + (size_t)bh * SDIM * DDIM;
#pragma unroll
    for (int i = 0; i < 4; ++i) {
        int r = y + i * 8;
        t[r][x] = Vb[(size_t)(s0 + r) * DDIM + d0 + x];
    }
    __syncthreads();
#pragma unroll
    for (int i = 0; i < 4; ++i) {
        int r = y + i * 8;
        Vtb[(size_t)(d0 + r) * SDIM + s0 + x] = (unsigned short)f2bf(t[x][r]);
    }
}

// ---- staging helpers (rule #21: linear LDS dest, inverse-swizzled global src) ----
static __device__ __forceinline__ void stage_K(const unsigned short* __restrict__ Kb,
                                               char* __restrict__ Kdst,
                                               int k0, int wave, int quad, int n16)
{
#pragma unroll
    for (int j = 0; j < 4; ++j) {               // wave covers K rows [wave*16, +16)
        const int row = wave * 16 + j * 4 + quad;
        const int src = (n16 * 16) ^ ((row & 7) << 4);
        const char* gp = (const char*)(Kb + (size_t)(k0 + row) * DDIM) + src;
        __builtin_amdgcn_global_load_lds((gvp)gp, (lvp)(Kdst + wave * 4096 + j * 1024), 16, 0, 0);
    }
}
static __device__ __forceinline__ void stage_V(const unsigned short* __restrict__ Vb,
                                               char* __restrict__ Vdst,
                                               int k0, int wave, int lane)
{
#pragma unroll
    for (int j = 0; j < 4; ++j) {               // wave covers V^T rows [wave*32, +32)
        const int row = wave * 32 + j * 8 + (lane >> 3);
        const int src = ((lane & 7) * 16) ^ ((row & 7) << 4);
        const char* gp = (const char*)(Vb + (size_t)row * SDIM + k0) + src;
        __builtin_amdgcn_global_load_lds((gvp)gp, (lvp)(Vdst + wave * 4096 + j * 1024), 16, 0, 0);
    }
}

// ---- mask tile load (slow path only) ----
static __device__ __forceinline__ void load_mask(const float* __restrict__ Mb,
                                                 int q0, int wave, int quad, int n16,
                                                 int kcol, float (&mk)[2][4][4])
{
#pragma unroll
    for (int rt = 0; rt < 2; ++rt) {
        const int rowb = q0 + wave * 32 + rt * 16 + quad * 4;
        const float* mpb = Mb + (size_t)rowb * SDIM + kcol + n16;
#pragma unroll
        for (int ct = 0; ct < 4; ++ct)
#pragma unroll
            for (int r = 0; r < 4; ++r)
                mk[rt][ct][r] = mpb[(size_t)r * SDIM + ct * 16];
    }
}

// ---- shared compute pieces ----
static __device__ __forceinline__ void softmax_update(
    f32x4 (&s)[2][4], f32x4 (&acc)[2][8], float (&mrow)[2][4], float (&lrow)[2][4])
{
    float mx[2][4];
#pragma unroll
    for (int rt = 0; rt < 2; ++rt)
#pragma unroll
        for (int r = 0; r < 4; ++r)
            mx[rt][r] = fmaxf(fmaxf(s[rt][0][r], s[rt][1][r]),
                              fmaxf(s[rt][2][r], s[rt][3][r]));
#pragma unroll
    for (int st = 1; st <= 8; st <<= 1)
#pragma unroll
        for (int rt = 0; rt < 2; ++rt)
#pragma unroll
            for (int r = 0; r < 4; ++r)
                mx[rt][r] = fmaxf(mx[rt][r], __shfl_xor(mx[rt][r], st));

    // exact defer-rescale: if no row sees a new max, al==1.0 -> skip is bitwise id.
    int anynew = 0;
#pragma unroll
    for (int rt = 0; rt < 2; ++rt)
#pragma unroll
        for (int r = 0; r < 4; ++r)
            anynew |= (mx[rt][r] > mrow[rt][r]) ? 1 : 0;
    if (__ballot(anynew) != 0ull) {
#pragma unroll
        for (int rt = 0; rt < 2; ++rt)
#pragma unroll
            for (int r = 0; r < 4; ++r) {
                float mnew = fmaxf(mrow[rt][r], mx[rt][r]);
                float al = exp2f((mrow[rt][r] - mnew) * 1.44269504f);
                mrow[rt][r] = mnew;
                lrow[rt][r] *= al;
#pragma unroll
                for (int nt = 0; nt < 8; ++nt) acc[rt][nt][r] *= al;
            }
    }

    float rs[2][4];
#pragma unroll
    for (int rt = 0; rt < 2; ++rt)
#pragma unroll
        for (int r = 0; r < 4; ++r) {
            float t = 0.f;
#pragma unroll
            for (int ct = 0; ct < 4; ++ct) {
                float pv = exp2f((s[rt][ct][r] - mrow[rt][r]) * 1.44269504f);
                s[rt][ct][r] = pv;
                t += pv;
            }
            rs[rt][r] = t;
        }
#pragma unroll
    for (int st = 1; st <= 8; st <<= 1)
#pragma unroll
        for (int rt = 0; rt < 2; ++rt)
#pragma unroll
            for (int r = 0; r < 4; ++r)
                rs[rt][r] += __shfl_xor(rs[rt][r], st);
#pragma unroll
    for (int rt = 0; rt < 2; ++rt)
#pragma unroll
        for (int r = 0; r < 4; ++r)
            lrow[rt][r] += rs[rt][r];
}

static __device__ __forceinline__ void qk_phase(
    const char* __restrict__ Kcur, int quad, int n16, int swzr,
    const bf16x8 (&qf)[2][4], f32x4 (&s)[2][4])
{
#pragma unroll
    for (int dt = 0; dt < 4; ++dt) {
        bf16x8 kf[4];
#pragma unroll
        for (int ct = 0; ct < 4; ++ct)
            kf[ct] = *(const bf16x8*)(Kcur + (ct * 16 + n16) * 256 +
                                      ((dt * 64 + quad * 16) ^ swzr));
        __builtin_amdgcn_s_setprio(1);
#pragma unroll
        for (int ct = 0; ct < 4; ++ct) {
            s[0][ct] = __builtin_amdgcn_mfma_f32_16x16x32_bf16(qf[0][dt], kf[ct], s[0][ct], 0, 0, 0);
            s[1][ct] = __builtin_amdgcn_mfma_f32_16x16x32_bf16(qf[1][dt], kf[ct], s[1][ct], 0, 0, 0);
        }
        __builtin_amdgcn_s_setprio(0);
    }
}

static __device__ __forceinline__ void ppack_pv(
    f32x4 (&s)[2][4], const char* __restrict__ Vl,
    unsigned short* __restrict__ PsW, int quad, int n16, int lane, int swzr,
    f32x4 (&acc)[2][8], bool deferred_barrier)
{
    // P: C-layout regs -> LDS (own wave region; no barrier needed)
#pragma unroll
    for (int rt = 0; rt < 2; ++rt)
#pragma unroll
        for (int ct = 0; ct < 4; ++ct)
#pragma unroll
            for (int r = 0; r < 4; ++r)
                PsW[(rt * 16 + (lane >> 4) * 4 + r) * PSTRIDE + ct * 16 + n16] =
                    (unsigned short)f2bf(s[rt][ct][r]);

    bf16x8 pa[2][2];
#pragma unroll
    for (int rt = 0; rt < 2; ++rt)
#pragma unroll
        for (int kt = 0; kt < 2; ++kt)
            pa[rt][kt] = *(const bf16x8*)(&PsW[(rt * 16 + n16) * PSTRIDE + kt * 32 + quad * 8]);

    if (deferred_barrier) {
        // V(i) drain deferred to here: covered by QK+softmax (~1000cy).
        // vmcnt(4) lets the K(i+1) prefetch stay in flight across the barrier.
        asm volatile("s_waitcnt vmcnt(4)" ::: "memory");
        __builtin_amdgcn_s_barrier();
    }

#pragma unroll
    for (int nt = 0; nt < 8; ++nt) {
        bf16x8 vf[2];
#pragma unroll
        for (int kt = 0; kt < 2; ++kt)
            vf[kt] = *(const bf16x8*)(Vl + (nt * 16 + n16) * 128 +
                                      ((kt * 64 + quad * 16) ^ swzr));
        __builtin_amdgcn_s_setprio(1);
#pragma unroll
        for (int kt = 0; kt < 2; ++kt) {
            acc[0][nt] = __builtin_amdgcn_mfma_f32_16x16x32_bf16(pa[0][kt], vf[kt], acc[0][nt], 0, 0, 0);
            acc[1][nt] = __builtin_amdgcn_mfma_f32_16x16x32_bf16(pa[1][kt], vf[kt], acc[1][nt], 0, 0, 0);
        }
        __builtin_amdgcn_s_setprio(0);
    }
}

// ---- fast tile: K prefetched one tile ahead (dbuf), V staged here with
//      deferred counted drain. Entry invariant: vmcnt==0, all waves past a
//      barrier with K(i) fully staged in Kcur. ----
static __device__ __forceinline__ void ktile_fast(
    int k0, int wave, int quad, int n16, int lane,
    const unsigned short* __restrict__ Kb, const unsigned short* __restrict__ Vb,
    char* __restrict__ Kcur, char* __restrict__ Knxt, char* __restrict__ Vl,
    unsigned short* __restrict__ PsW,
    const bf16x8 (&qf)[2][4],
    f32x4 (&acc)[2][8], float (&mrow)[2][4], float (&lrow)[2][4])
{
    const f32x4 zero4 = {0.f, 0.f, 0.f, 0.f};

    stage_V(Vb, Vl, k0, wave, lane);                       // 4 loads
    stage_K(Kb, Knxt, (k0 + BC) & (SDIM - 1), wave, quad, n16);  // 4 loads

    const int swzr = (n16 & 7) << 4;

    f32x4 s[2][4];
#pragma unroll
    for (int rt = 0; rt < 2; ++rt)
#pragma unroll
        for (int ct = 0; ct < 4; ++ct) s[rt][ct] = zero4;

    qk_phase(Kcur, quad, n16, swzr, qf, s);                // no wait needed: K(i) ready
    softmax_update(s, acc, mrow, lrow);
    ppack_pv(s, Vl, PsW, quad, n16, lane, swzr, acc, true); // vmcnt(4)+barrier inside

    // end of tile: drain K(i+1) (stale, ~2000cy old -> free) and release Vl/Kcur
    asm volatile("s_waitcnt vmcnt(0)" ::: "memory");
    __builtin_amdgcn_s_barrier();
}

// ---- masked tile: round-5 verified __syncthreads structure ----
static __device__ __forceinline__ void ktile_masked(
    int k0, int q0, int wave, int quad, int n16, int lane,
    const float* __restrict__ Mb,
    const unsigned short* __restrict__ Kb, const unsigned short* __restrict__ Vb,
    char* __restrict__ Kl, char* __restrict__ Vl,
    unsigned short* __restrict__ PsW,
    const bf16x8 (&qf)[2][4],
    f32x4 (&acc)[2][8], float (&mrow)[2][4], float (&lrow)[2][4])
{
    const f32x4 zero4 = {0.f, 0.f, 0.f, 0.f};

    stage_K(Kb, Kl, k0, wave, quad, n16);
    stage_V(Vb, Vl, k0, wave, lane);

    float mk[2][4][4];
    load_mask(Mb, q0, wave, quad, n16, k0, mk);

    __syncthreads();   // drains vmcnt (stages + mask) and lgkm

    const int swzr = (n16 & 7) << 4;

    f32x4 s[2][4];
#pragma unroll
    for (int rt = 0; rt < 2; ++rt)
#pragma unroll
        for (int ct = 0; ct < 4; ++ct) s[rt][ct] = zero4;

    qk_phase(Kl, quad, n16, swzr, qf, s);

#pragma unroll
    for (int rt = 0; rt < 2; ++rt)
#pragma unroll
        for (int ct = 0; ct < 4; ++ct)
#pragma unroll
            for (int r = 0; r < 4; ++r)
                s[rt][ct][r] += mk[rt][ct][r];

    softmax_update(s, acc, mrow, lrow);
    ppack_pv(s, Vl, PsW, quad, n16, lane, swzr, acc, false);
}

// ---- main: flash attention; fused per-block mask zero-scan ----
__global__ __launch_bounds__(256, 2) void fattn_kernel(
    const float* __restrict__ Q, const float* __restrict__ M,
    const unsigned short* __restrict__ Kc, const unsigned short* __restrict__ Vt,
    float* __restrict__ O)
{
    // XCD-grouped decode: all 16 q-tiles of one bh share flat%8 -> one XCD's L2
    const int flat = blockIdx.x;
    const int slot = flat >> 3;
    const int bh   = (flat & 7) * 8 + (slot >> 4);
    const int qt   = slot & 15;

    const int tid  = threadIdx.x;
    const int wave = tid >> 6;
    const int lane = tid & 63;
    const int quad = lane >> 4;
    const int n16  = lane & 15;
    const int q0   = qt * BR;

    const float* Qb = Q + (size_t)bh * SDIM * DDIM;
    const float* Mb = M + (size_t)bh * SDIM * SDIM;
    const unsigned short* Kb = Kc + (size_t)bh * SDIM * DDIM;  // [s][d] bf16
    const unsigned short* Vb = Vt + (size_t)bh * SDIM * DDIM;  // [d][s] bf16
    float* Ob = O + (size_t)bh * SDIM * DDIM;

    __shared__ __align__(16) char Kl0[64 * 256];                      // 16 KB
    __shared__ __align__(16) char Kl1[64 * 256];                      // 16 KB
    __shared__ __align__(16) char Vl[128 * 128];                      // 16 KB
    __shared__ __align__(16) unsigned short Ps[4][32 * PSTRIDE];      // 18 KB
    __shared__ int blkmask;
    unsigned short* PsW = Ps[wave];

    // issue K(0) prefetch immediately; its latency hides under the scan below
    stage_K(Kb, Kl0, 0, wave, quad, n16);

    // Q A-fragments, pre-scaled, in regs for the whole kernel
    const float scale = 0.08838834764831845f;
    bf16x8 qf[2][4];
#pragma unroll
    for (int rt = 0; rt < 2; ++rt) {
        int row = q0 + wave * 32 + rt * 16 + n16;
        const float* qp = Qb + (size_t)row * DDIM + quad * 8;
#pragma unroll
        for (int dt = 0; dt < 4; ++dt) {
            const float* p = qp + dt * 32;
            float4 a = *(const float4*)p;
            float4 b = *(const float4*)(p + 4);
            bf16x8 f;
            f[0] = f2bf(a.x * scale); f[1] = f2bf(a.y * scale);
            f[2] = f2bf(a.z * scale); f[3] = f2bf(a.w * scale);
            f[4] = f2bf(b.x * scale); f[5] = f2bf(b.y * scale);
            f[6] = f2bf(b.z * scale); f[7] = f2bf(b.w * scale);
            qf[rt][dt] = f;
        }
    }

    // ---- fused mask zero-scan: this block's 1 MB slice (rows q0..q0+127).
    //      Bitwise-nonzero is conservative: -0.0/NaN/Inf -> exact slow path. ----
    if (tid == 0) blkmask = 0;
    {
        const uint4* Ms = (const uint4*)(Mb + (size_t)q0 * SDIM);
        unsigned a0 = 0, a1 = 0, a2 = 0, a3 = 0;
#pragma unroll 1
        for (int i = tid; i < (BR * SDIM / 4); i += 1024) {
            uint4 v0 = Ms[i];
            uint4 v1 = Ms[i + 256];
            uint4 v2 = Ms[i + 512];
            uint4 v3 = Ms[i + 768];
            a0 |= v0.x | v0.y | v0.z | v0.w;
            a1 |= v1.x | v1.y | v1.z | v1.w;
            a2 |= v2.x | v2.y | v2.z | v2.w;
            a3 |= v3.x | v3.y | v3.z | v3.w;
        }
        const unsigned am = (a0 | a1) | (a2 | a3);
        __syncthreads();                 // blkmask init visible
        if (am) atomicOr(&blkmask, 1);   // zeros case: never executes
    }
    __syncthreads();                     // flag ready; also drains K(0) stage (vmcnt 0)
    const bool masked = (blkmask != 0);  // block-uniform

    f32x4 acc[2][8];
    const f32x4 zero4 = {0.f, 0.f, 0.f, 0.f};
#pragma unroll
    for (int rt = 0; rt < 2; ++rt)
#pragma unroll
        for (int nt = 0; nt < 8; ++nt) acc[rt][nt] = zero4;
    float mrow[2][4], lrow[2][4];
#pragma unroll
    for (int rt = 0; rt < 2; ++rt)
#pragma unroll
        for (int r = 0; r < 4; ++r) { mrow[rt][r] = -1e30f; lrow[rt][r] = 0.f; }

    if (!masked) {
        // entry invariant holds: vmcnt drained, barrier passed, K(0) in Kl0
#pragma unroll 1
        for (int k0 = 0; k0 < SDIM; k0 += 2 * BC) {
            ktile_fast(k0,      wave, quad, n16, lane, Kb, Vb, Kl0, Kl1, Vl,
                       PsW, qf, acc, mrow, lrow);
            ktile_fast(k0 + BC, wave, quad, n16, lane, Kb, Vb, Kl1, Kl0, Vl,
                       PsW, qf, acc, mrow, lrow);
        }
    } else {
#pragma unroll 1
        for (int k0 = 0; k0 < SDIM; k0 += BC) {
            __syncthreads();   // Kl0/Vl free (prev tile's ds_reads done)
            ktile_masked(k0, q0, wave, quad, n16, lane, Mb, Kb, Vb, Kl0, Vl,
                         PsW, qf, acc, mrow, lrow);
        }
    }

    // ---- epilogue ----
#pragma unroll
    for (int rt = 0; rt < 2; ++rt) {
#pragma unroll
        for (int r = 0; r < 4; ++r) {
            float inv = 1.0f / lrow[rt][r];
            int row = q0 + wave * 32 + rt * 16 + quad * 4 + r;
            float* op = Ob + (size_t)row * DDIM + n16;
#pragma unroll
            for (int nt = 0; nt < 8; ++nt)
                op[nt * 16] = acc[rt][nt][r] * inv;
        }
    }
}

extern "C" void kernel_launch(void* const* d_in, const int* in_sizes, int n_in,
                              void* d_out, int out_size, void* d_ws, size_t ws_size,
                              hipStream_t stream) {
    const float* Q = (const float*)d_in[0];
    const float* K = (const float*)d_in[1];
    const float* V = (const float*)d_in[2];
    const float* M = (const float*)d_in[3];
    float* O = (float*)d_out;

    const size_t nElem = (size_t)NBH * SDIM * DDIM;      // 16.7M elems per array
    unsigned short* Kc = (unsigned short*)d_ws;
    unsigned short* Vt = Kc + nElem;

    kconv_kernel<<<dim3(nElem / (256 * 4)), 256, 0, stream>>>(K, Kc);
    vtrans_kernel<<<dim3(SDIM / 32, DDIM / 32, NBH), 256, 0, stream>>>(V, Vt);
    fattn_kernel<<<dim3((SDIM / BR) * NBH), 256, 0, stream>>>(Q, M, Kc, Vt, O);
}

// Round 7
// 1597.146 us; speedup vs baseline: 1.2418x; 1.0866x over previous
//
#include <hip/hip_runtime.h>

#define SDIM 2048
#define DDIM 128
#define NBH  64
#define BR   128   // q rows per block (4 waves x 32)
#define BC   64    // keys per tile
#define PSTRIDE 72 // bf16 elems; conflict-free b128 A-frag reads of P

using bf16x8 = __attribute__((ext_vector_type(8))) short;
using f32x4  = __attribute__((ext_vector_type(4))) float;

typedef const __attribute__((address_space(1))) void* gvp;
typedef __attribute__((address_space(3))) void* lvp;

static __device__ __forceinline__ short f2bf(float x) {
    unsigned u = __float_as_uint(x);
    u += 0x7fff + ((u >> 16) & 1);   // RNE
    return (short)(u >> 16);
}
static __device__ __forceinline__ unsigned pack2(float a, float b) {
    return ((unsigned)(unsigned short)f2bf(a)) |
           (((unsigned)(unsigned short)f2bf(b)) << 16);
}

// ---- prep 1: K fp32 -> bf16 (elementwise) ----
__global__ __launch_bounds__(256) void kconv_kernel(const float* __restrict__ K,
                                                    unsigned short* __restrict__ Kc)
{
    size_t i = ((size_t)blockIdx.x * 256 + threadIdx.x) * 4;
    float4 v = *(const float4*)(K + i);
    uint2 o;
    o.x = pack2(v.x, v.y);
    o.y = pack2(v.z, v.w);
    *(uint2*)(Kc + i) = o;
}

// ---- prep 2: V fp32 [bh][s][d] -> bf16 V^T [bh][d][s] ----
__global__ __launch_bounds__(256) void vtrans_kernel(const float* __restrict__ V,
                                                     unsigned short* __restrict__ Vt)
{
    __shared__ float t[32][33];
    const int bh = blockIdx.z;
    const int s0 = blockIdx.x * 32;
    const int d0 = blockIdx.y * 32;
    const int x = threadIdx.x & 31;
    const int y = threadIdx.x >> 5;
    const float* Vb = V + (size_t)bh * SDIM * DDIM;
    unsigned short* Vtb = Vt + (size_t)bh * SDIM * DDIM;
#pragma unroll
    for (int i = 0; i < 4; ++i) {
        int r = y + i * 8;
        t[r][x] = Vb[(size_t)(s0 + r) * DDIM + d0 + x];
    }
    __syncthreads();
#pragma unroll
    for (int i = 0; i < 4; ++i) {
        int r = y + i * 8;
        Vtb[(size_t)(d0 + r) * SDIM + s0 + x] = (unsigned short)f2bf(t[x][r]);
    }
}

// ---- staging helpers (rule #21: linear LDS dest, inverse-swizzled global src) ----
static __device__ __forceinline__ void stage_K(const unsigned short* __restrict__ Kb,
                                               char* __restrict__ Kdst,
                                               int k0, int wave, int quad, int n16)
{
#pragma unroll
    for (int j = 0; j < 4; ++j) {               // wave covers K rows [wave*16, +16)
        const int row = wave * 16 + j * 4 + quad;
        const int src = (n16 * 16) ^ ((row & 7) << 4);
        const char* gp = (const char*)(Kb + (size_t)(k0 + row) * DDIM) + src;
        __builtin_amdgcn_global_load_lds((gvp)gp, (lvp)(Kdst + wave * 4096 + j * 1024), 16, 0, 0);
    }
}
static __device__ __forceinline__ void stage_V(const unsigned short* __restrict__ Vb,
                                               char* __restrict__ Vdst,
                                               int k0, int wave, int lane)
{
#pragma unroll
    for (int j = 0; j < 4; ++j) {               // wave covers V^T rows [wave*32, +32)
        const int row = wave * 32 + j * 8 + (lane >> 3);
        const int src = ((lane & 7) * 16) ^ ((row & 7) << 4);
        const char* gp = (const char*)(Vb + (size_t)row * SDIM + k0) + src;
        __builtin_amdgcn_global_load_lds((gvp)gp, (lvp)(Vdst + wave * 4096 + j * 1024), 16, 0, 0);
    }
}

// ---- mask tile load: 32 coalesced dwords; layout matches the verified C layout ----
static __device__ __forceinline__ void load_mask(const float* __restrict__ Mb,
                                                 int q0, int wave, int quad, int n16,
                                                 int kcol, float (&mk)[2][4][4])
{
#pragma unroll
    for (int rt = 0; rt < 2; ++rt) {
        const int rowb = q0 + wave * 32 + rt * 16 + quad * 4;
        const float* mpb = Mb + (size_t)rowb * SDIM + kcol + n16;
#pragma unroll
        for (int ct = 0; ct < 4; ++ct)
#pragma unroll
            for (int r = 0; r < 4; ++r)
                mk[rt][ct][r] = mpb[(size_t)r * SDIM + ct * 16];
    }
}

// ---- shared compute pieces ----
static __device__ __forceinline__ void softmax_update(
    f32x4 (&s)[2][4], f32x4 (&acc)[2][8], float (&mrow)[2][4], float (&lrow)[2][4])
{
    float mx[2][4];
#pragma unroll
    for (int rt = 0; rt < 2; ++rt)
#pragma unroll
        for (int r = 0; r < 4; ++r)
            mx[rt][r] = fmaxf(fmaxf(s[rt][0][r], s[rt][1][r]),
                              fmaxf(s[rt][2][r], s[rt][3][r]));
#pragma unroll
    for (int st = 1; st <= 8; st <<= 1)
#pragma unroll
        for (int rt = 0; rt < 2; ++rt)
#pragma unroll
            for (int r = 0; r < 4; ++r)
                mx[rt][r] = fmaxf(mx[rt][r], __shfl_xor(mx[rt][r], st));

    // exact defer-rescale: if no row sees a new max, al==1.0 -> skip is bitwise id.
    int anynew = 0;
#pragma unroll
    for (int rt = 0; rt < 2; ++rt)
#pragma unroll
        for (int r = 0; r < 4; ++r)
            anynew |= (mx[rt][r] > mrow[rt][r]) ? 1 : 0;
    if (__ballot(anynew) != 0ull) {
#pragma unroll
        for (int rt = 0; rt < 2; ++rt)
#pragma unroll
            for (int r = 0; r < 4; ++r) {
                float mnew = fmaxf(mrow[rt][r], mx[rt][r]);
                float al = exp2f((mrow[rt][r] - mnew) * 1.44269504f);
                mrow[rt][r] = mnew;
                lrow[rt][r] *= al;
#pragma unroll
                for (int nt = 0; nt < 8; ++nt) acc[rt][nt][r] *= al;
            }
    }

    float rs[2][4];
#pragma unroll
    for (int rt = 0; rt < 2; ++rt)
#pragma unroll
        for (int r = 0; r < 4; ++r) {
            float t = 0.f;
#pragma unroll
            for (int ct = 0; ct < 4; ++ct) {
                float pv = exp2f((s[rt][ct][r] - mrow[rt][r]) * 1.44269504f);
                s[rt][ct][r] = pv;
                t += pv;
            }
            rs[rt][r] = t;
        }
#pragma unroll
    for (int st = 1; st <= 8; st <<= 1)
#pragma unroll
        for (int rt = 0; rt < 2; ++rt)
#pragma unroll
            for (int r = 0; r < 4; ++r)
                rs[rt][r] += __shfl_xor(rs[rt][r], st);
#pragma unroll
    for (int rt = 0; rt < 2; ++rt)
#pragma unroll
        for (int r = 0; r < 4; ++r)
            lrow[rt][r] += rs[rt][r];
}

static __device__ __forceinline__ void qk_phase(
    const char* __restrict__ Kcur, int quad, int n16, int swzr,
    const bf16x8 (&qf)[2][4], f32x4 (&s)[2][4])
{
#pragma unroll
    for (int dt = 0; dt < 4; ++dt) {
        bf16x8 kf[4];
#pragma unroll
        for (int ct = 0; ct < 4; ++ct)
            kf[ct] = *(const bf16x8*)(Kcur + (ct * 16 + n16) * 256 +
                                      ((dt * 64 + quad * 16) ^ swzr));
        __builtin_amdgcn_s_setprio(1);
#pragma unroll
        for (int ct = 0; ct < 4; ++ct) {
            s[0][ct] = __builtin_amdgcn_mfma_f32_16x16x32_bf16(qf[0][dt], kf[ct], s[0][ct], 0, 0, 0);
            s[1][ct] = __builtin_amdgcn_mfma_f32_16x16x32_bf16(qf[1][dt], kf[ct], s[1][ct], 0, 0, 0);
        }
        __builtin_amdgcn_s_setprio(0);
    }
}

static __device__ __forceinline__ void ppack_pv(
    f32x4 (&s)[2][4], const char* __restrict__ Vl,
    unsigned short* __restrict__ PsW, int quad, int n16, int lane, int swzr,
    f32x4 (&acc)[2][8])
{
    // P: C-layout regs -> LDS (own wave region; no barrier needed)
#pragma unroll
    for (int rt = 0; rt < 2; ++rt)
#pragma unroll
        for (int ct = 0; ct < 4; ++ct)
#pragma unroll
            for (int r = 0; r < 4; ++r)
                PsW[(rt * 16 + (lane >> 4) * 4 + r) * PSTRIDE + ct * 16 + n16] =
                    (unsigned short)f2bf(s[rt][ct][r]);

    bf16x8 pa[2][2];
#pragma unroll
    for (int rt = 0; rt < 2; ++rt)
#pragma unroll
        for (int kt = 0; kt < 2; ++kt)
            pa[rt][kt] = *(const bf16x8*)(&PsW[(rt * 16 + n16) * PSTRIDE + kt * 32 + quad * 8]);

    // V(i) drain deferred to here: covered by QK+softmax (~1000cy).
    // vmcnt(4) lets the K(i+1) prefetch stay in flight across the barrier.
    // (mask loads retired earlier by the compiler's own wait before the add)
    asm volatile("s_waitcnt vmcnt(4)" ::: "memory");
    __builtin_amdgcn_s_barrier();

#pragma unroll
    for (int nt = 0; nt < 8; ++nt) {
        bf16x8 vf[2];
#pragma unroll
        for (int kt = 0; kt < 2; ++kt)
            vf[kt] = *(const bf16x8*)(Vl + (nt * 16 + n16) * 128 +
                                      ((kt * 64 + quad * 16) ^ swzr));
        __builtin_amdgcn_s_setprio(1);
#pragma unroll
        for (int kt = 0; kt < 2; ++kt) {
            acc[0][nt] = __builtin_amdgcn_mfma_f32_16x16x32_bf16(pa[0][kt], vf[kt], acc[0][nt], 0, 0, 0);
            acc[1][nt] = __builtin_amdgcn_mfma_f32_16x16x32_bf16(pa[1][kt], vf[kt], acc[1][nt], 0, 0, 0);
        }
        __builtin_amdgcn_s_setprio(0);
    }
}

// ---- one k-tile, unified path: mask streamed in-loop (BW overlaps compute).
//      Entry invariant: vmcnt==0, all waves past a barrier, K(i) staged in Kcur. ----
static __device__ __forceinline__ void ktile(
    int k0, int q0, int wave, int quad, int n16, int lane,
    const float* __restrict__ Mb,
    const unsigned short* __restrict__ Kb, const unsigned short* __restrict__ Vb,
    char* __restrict__ Kcur, char* __restrict__ Knxt, char* __restrict__ Vl,
    unsigned short* __restrict__ PsW,
    const bf16x8 (&qf)[2][4],
    f32x4 (&acc)[2][8], float (&mrow)[2][4], float (&lrow)[2][4])
{
    const f32x4 zero4 = {0.f, 0.f, 0.f, 0.f};

    // mask tile FIRST (32 dwords), pinned before the stages so the auto-wait
    // for the mask-add is vmcnt(8) and the staging loads stay in flight.
    float mk[2][4][4];
    load_mask(Mb, q0, wave, quad, n16, k0, mk);
    __builtin_amdgcn_sched_barrier(0);

    stage_V(Vb, Vl, k0, wave, lane);                             // 4 loads
    stage_K(Kb, Knxt, (k0 + BC) & (SDIM - 1), wave, quad, n16);  // 4 loads
    __builtin_amdgcn_sched_barrier(0);

    const int swzr = (n16 & 7) << 4;

    f32x4 s[2][4];
#pragma unroll
    for (int rt = 0; rt < 2; ++rt)
#pragma unroll
        for (int ct = 0; ct < 4; ++ct) s[rt][ct] = zero4;

    qk_phase(Kcur, quad, n16, swzr, qf, s);   // no wait: K(i) ready on entry

    // mask add: +0.0f is identity through exp -> exact for the zero-mask case
#pragma unroll
    for (int rt = 0; rt < 2; ++rt)
#pragma unroll
        for (int ct = 0; ct < 4; ++ct)
#pragma unroll
            for (int r = 0; r < 4; ++r)
                s[rt][ct][r] += mk[rt][ct][r];

    softmax_update(s, acc, mrow, lrow);
    ppack_pv(s, Vl, PsW, quad, n16, lane, swzr, acc);   // vmcnt(4)+barrier inside

    // end of tile: drain K(i+1) (issued ~3000cy ago -> free) and release Vl/Kcur
    asm volatile("s_waitcnt vmcnt(0)" ::: "memory");
    __builtin_amdgcn_s_barrier();
}

// ---- main: flash attention, single path, mask streamed under compute ----
__global__ __launch_bounds__(256, 2) void fattn_kernel(
    const float* __restrict__ Q, const float* __restrict__ M,
    const unsigned short* __restrict__ Kc, const unsigned short* __restrict__ Vt,
    float* __restrict__ O)
{
    // XCD-grouped decode: all 16 q-tiles of one bh share flat%8 -> one XCD's L2
    const int flat = blockIdx.x;
    const int slot = flat >> 3;
    const int bh   = (flat & 7) * 8 + (slot >> 4);
    const int qt   = slot & 15;

    const int tid  = threadIdx.x;
    const int wave = tid >> 6;
    const int lane = tid & 63;
    const int quad = lane >> 4;
    const int n16  = lane & 15;
    const int q0   = qt * BR;

    const float* Qb = Q + (size_t)bh * SDIM * DDIM;
    const float* Mb = M + (size_t)bh * SDIM * SDIM;
    const unsigned short* Kb = Kc + (size_t)bh * SDIM * DDIM;  // [s][d] bf16
    const unsigned short* Vb = Vt + (size_t)bh * SDIM * DDIM;  // [d][s] bf16
    float* Ob = O + (size_t)bh * SDIM * DDIM;

    __shared__ __align__(16) char Kl0[64 * 256];                      // 16 KB
    __shared__ __align__(16) char Kl1[64 * 256];                      // 16 KB
    __shared__ __align__(16) char Vl[128 * 128];                      // 16 KB
    __shared__ __align__(16) unsigned short Ps[4][32 * PSTRIDE];      // 18 KB
    unsigned short* PsW = Ps[wave];

    // issue K(0) prefetch immediately; its latency hides under Q-frag prep
    stage_K(Kb, Kl0, 0, wave, quad, n16);

    // Q A-fragments, pre-scaled, in regs for the whole kernel
    const float scale = 0.08838834764831845f;
    bf16x8 qf[2][4];
#pragma unroll
    for (int rt = 0; rt < 2; ++rt) {
        int row = q0 + wave * 32 + rt * 16 + n16;
        const float* qp = Qb + (size_t)row * DDIM + quad * 8;
#pragma unroll
        for (int dt = 0; dt < 4; ++dt) {
            const float* p = qp + dt * 32;
            float4 a = *(const float4*)p;
            float4 b = *(const float4*)(p + 4);
            bf16x8 f;
            f[0] = f2bf(a.x * scale); f[1] = f2bf(a.y * scale);
            f[2] = f2bf(a.z * scale); f[3] = f2bf(a.w * scale);
            f[4] = f2bf(b.x * scale); f[5] = f2bf(b.y * scale);
            f[6] = f2bf(b.z * scale); f[7] = f2bf(b.w * scale);
            qf[rt][dt] = f;
        }
    }

    f32x4 acc[2][8];
    const f32x4 zero4 = {0.f, 0.f, 0.f, 0.f};
#pragma unroll
    for (int rt = 0; rt < 2; ++rt)
#pragma unroll
        for (int nt = 0; nt < 8; ++nt) acc[rt][nt] = zero4;
    float mrow[2][4], lrow[2][4];
#pragma unroll
    for (int rt = 0; rt < 2; ++rt)
#pragma unroll
        for (int r = 0; r < 4; ++r) { mrow[rt][r] = -1e30f; lrow[rt][r] = 0.f; }

    // establish loop entry invariant: K(0) staged, vmcnt drained, barrier passed
    asm volatile("s_waitcnt vmcnt(0)" ::: "memory");
    __builtin_amdgcn_s_barrier();

#pragma unroll 1
    for (int k0 = 0; k0 < SDIM; k0 += 2 * BC) {
        ktile(k0,      q0, wave, quad, n16, lane, Mb, Kb, Vb, Kl0, Kl1, Vl,
              PsW, qf, acc, mrow, lrow);
        ktile(k0 + BC, q0, wave, quad, n16, lane, Mb, Kb, Vb, Kl1, Kl0, Vl,
              PsW, qf, acc, mrow, lrow);
    }

    // ---- epilogue ----
#pragma unroll
    for (int rt = 0; rt < 2; ++rt) {
#pragma unroll
        for (int r = 0; r < 4; ++r) {
            float inv = 1.0f / lrow[rt][r];
            int row = q0 + wave * 32 + rt * 16 + quad * 4 + r;
            float* op = Ob + (size_t)row * DDIM + n16;
#pragma unroll
            for (int nt = 0; nt < 8; ++nt)
                op[nt * 16] = acc[rt][nt][r] * inv;
        }
    }
}

extern "C" void kernel_launch(void* const* d_in, const int* in_sizes, int n_in,
                              void* d_out, int out_size, void* d_ws, size_t ws_size,
                              hipStream_t stream) {
    const float* Q = (const float*)d_in[0];
    const float* K = (const float*)d_in[1];
    const float* V = (const float*)d_in[2];
    const float* M = (const float*)d_in[3];
    float* O = (float*)d_out;

    const size_t nElem = (size_t)NBH * SDIM * DDIM;      // 16.7M elems per array
    unsigned short* Kc = (unsigned short*)d_ws;
    unsigned short* Vt = Kc + nElem;

    kconv_kernel<<<dim3(nElem / (256 * 4)), 256, 0, stream>>>(K, Kc);
    vtrans_kernel<<<dim3(SDIM / 32, DDIM / 32, NBH), 256, 0, stream>>>(V, Vt);
    fattn_kernel<<<dim3((SDIM / BR) * NBH), 256, 0, stream>>>(Q, M, Kc, Vt, O);
}